// Round 3
// baseline (250.221 us; speedup 1.0000x reference)
//
#include <hip/hip_runtime.h>
#include <math.h>

// Problem: E=8, B=4096, D=128, N=8192.
// out[b,n] = softmax_n( x[b,:] @ W[e(b)] + bias[e(b)] ) for the (unique) bin e(b), else 0.
//
// Round 3 = Round 2 structure with the plane-stride BUG FIXED:
//   wl = wh + E*N*D in the launcher, so whp -> wlp offset is E*N*D (8*N*D), NOT N*D.
//   Round 2 read W_hi of expert e+1 as "W_lo" -> O(1) logit corruption (absmax 0.163).
// Structure: 512 threads, 8 waves each owning a distinct 32-col slice (no B duplication),
//   W_hi fragment reused for both x_hi and x_lo MFMAs (B traffic /3), depth-1 B prefetch,
//   A resident in 64KB XOR-swizzled LDS, barrier-free K-loop.
// Numeric path: x*W ~= x_hi*W_hi + x_lo*W_hi + x_hi*W_lo (bf16 3-term split).

#define B_ROWS 4096
#define D_DIM  128
#define N_DIM  8192
#define E_NUM  8

typedef __attribute__((ext_vector_type(8))) __bf16 bf16x8;
typedef __attribute__((ext_vector_type(4))) float  f32x4;

__device__ __forceinline__ unsigned short f2bf(float f) {
    unsigned int u = __float_as_uint(f);
    unsigned int r = u + 0x7FFFu + ((u >> 16) & 1u);   // round-to-nearest-even
    return (unsigned short)(r >> 16);
}
__device__ __forceinline__ float bf2f(unsigned short h) {
    return __uint_as_float(((unsigned int)h) << 16);
}

// ws int layout:
//   [0]         n_tiles
//   [8..79]     tile_e
//   [96..167]   tile_start
//   [184..255]  tile_cnt
//   [448..455]  per-expert counts
//   [512..4607] sorted row indices (grouped by expert)
// byte 65536+ : x_hi (1MB) | x_lo (1MB) | W_hi (16MB) | W_lo (16MB)   [bf16]

__global__ __launch_bounds__(1024)
void bin_kernel(const float* __restrict__ x,
                const float* __restrict__ tlo,
                const float* __restrict__ thi,
                int* __restrict__ ws_i, int m_tile) {
    __shared__ int cnt_s[E_NUM];
    __shared__ int off_s[E_NUM];
    __shared__ int cur_s[E_NUM];
    __shared__ int e_row[B_ROWS];

    int tid = threadIdx.x;
    if (tid < E_NUM) cnt_s[tid] = 0;
    __syncthreads();

    for (int r = tid; r < B_ROWS; r += 1024) {
        float th = x[(size_t)r * D_DIM];   // x[r, 0]
        int e = -1;
        #pragma unroll
        for (int i = 0; i < E_NUM; ++i) {
            if (e < 0 && th > tlo[i] && th <= thi[i]) e = i;  // first match
        }
        e_row[r] = e;
        if (e >= 0) atomicAdd(&cnt_s[e], 1);
    }
    __syncthreads();

    if (tid == 0) {
        int off = 0;
        for (int e = 0; e < E_NUM; ++e) {
            ws_i[448 + e] = cnt_s[e];
            off_s[e] = off;
            cur_s[e] = off;
            off += cnt_s[e];
        }
        int nt = 0;
        for (int e = 0; e < E_NUM; ++e) {
            int c = cnt_s[e];
            int s = off_s[e];
            for (int t0 = 0; t0 < c && nt < 72; t0 += m_tile) {
                ws_i[8 + nt]   = e;
                ws_i[96 + nt]  = s + t0;
                ws_i[184 + nt] = (c - t0 < m_tile) ? (c - t0) : m_tile;
                ++nt;
            }
        }
        ws_i[0] = nt;
    }
    __syncthreads();

    for (int r = tid; r < B_ROWS; r += 1024) {
        int e = e_row[r];
        if (e >= 0) {
            int p = atomicAdd(&cur_s[e], 1);
            ws_i[512 + p] = r;
        }
    }
}

// Split x and active experts' W into bf16 hi/lo. W output layout is TRANSPOSED to
// [e][n][k] (k contiguous) so MFMA B-fragments are 16B contiguous loads.
__global__ __launch_bounds__(256)
void convert_kernel(const float* __restrict__ x, const float* __restrict__ W,
                    const int* __restrict__ ws_i,
                    unsigned short* __restrict__ xh, unsigned short* __restrict__ xl,
                    unsigned short* __restrict__ wh, unsigned short* __restrict__ wl) {
    int bid = blockIdx.x;
    int t = threadIdx.x;
    if (bid < 1024) {
        int e = bid >> 7;                       // 8 experts x 128 n-chunks of 64
        if (ws_i[448 + e] == 0) return;         // expert inactive -> skip
        int n0 = (bid & 127) * 64;
        __shared__ __align__(16) unsigned short hi_s[64][136];  // stride 272B
        __shared__ __align__(16) unsigned short lo_s[64][136];
        const float* Wp = W + (size_t)e * D_DIM * N_DIM + n0;
        #pragma unroll
        for (int i = 0; i < 8; ++i) {
            int idx = i * 256 + t;              // 2048 float4 = 128 d-rows x 16
            int d  = idx >> 4;
            int j4 = idx & 15;
            float4 v = *(const float4*)(Wp + (size_t)d * N_DIM + j4 * 4);
            float fv[4] = {v.x, v.y, v.z, v.w};
            #pragma unroll
            for (int c = 0; c < 4; ++c) {
                unsigned short h = f2bf(fv[c]);
                hi_s[j4 * 4 + c][d] = h;
                lo_s[j4 * 4 + c][d] = f2bf(fv[c] - bf2f(h));
            }
        }
        __syncthreads();
        unsigned short* whp = wh + ((size_t)e * N_DIM + n0) * D_DIM;
        unsigned short* wlp = wl + ((size_t)e * N_DIM + n0) * D_DIM;
        #pragma unroll
        for (int i = 0; i < 4; ++i) {
            int idx = i * 256 + t;              // 1024 16B-chunks = 64 n-rows x 16
            int nl = idx >> 4;
            int ck = idx & 15;
            *(uint4*)(whp + (size_t)nl * D_DIM + ck * 8) = *(const uint4*)(&hi_s[nl][ck * 8]);
            *(uint4*)(wlp + (size_t)nl * D_DIM + ck * 8) = *(const uint4*)(&lo_s[nl][ck * 8]);
        }
    } else {
        // x split: 16 blocks cover 4096*128 floats, layout unchanged (k contiguous)
        int base = (bid - 1024) * 32768;
        for (int i = 0; i < 32; ++i) {
            int idx = base + (i * 256 + t) * 4;
            float4 v = *(const float4*)(x + idx);
            float fv[4] = {v.x, v.y, v.z, v.w};
            unsigned short hq[4], lq[4];
            #pragma unroll
            for (int c = 0; c < 4; ++c) {
                hq[c] = f2bf(fv[c]);
                lq[c] = f2bf(fv[c] - bf2f(hq[c]));
            }
            *(uint2*)(xh + idx) = *(const uint2*)hq;
            *(uint2*)(xl + idx) = *(const uint2*)lq;
        }
    }
}

// MFMA GEMM v2: block = 128 rows x 256 cols, 512 threads = 8 waves in 1x8 col-split
// (each wave owns 32 distinct cols -> no B duplication across waves).
// K-loop: 8 steps. Steps 0..3: whp fragment reused for BOTH x_hi and x_lo MFMAs.
// Steps 4..7: wlp with x_hi. Depth-1 B prefetch. A resident in 64KB swizzled LDS.
__global__ __launch_bounds__(512, 4)
void gemm_mfma(const unsigned short* __restrict__ xh, const unsigned short* __restrict__ xl,
               const unsigned short* __restrict__ wh, const unsigned short* __restrict__ wl,
               const float* __restrict__ bias, const int* __restrict__ ws_i,
               float* __restrict__ out) {
    int bt = blockIdx.y;
    if (bt >= ws_i[0]) return;
    int e   = ws_i[8 + bt];
    int seg = ws_i[96 + bt];
    int cnt = ws_i[184 + bt];
    const int* sorted = ws_i + 512;

    __shared__ __align__(16) unsigned short a_s[2][128 * 128];  // 64 KB

    int tid = threadIdx.x;
    // stage gathered x_hi/x_lo rows, XOR-swizzled: byte ^= (row&7)<<4
    #pragma unroll
    for (int i = 0; i < 4; ++i) {
        int idx = i * 512 + tid;     // 2048 chunks = 128 rows x 16 x 16B
        int row = idx >> 4;
        int ck  = idx & 15;
        uint4 vh = make_uint4(0, 0, 0, 0), vl = make_uint4(0, 0, 0, 0);
        if (row < cnt) {
            int r = sorted[seg + row];
            vh = *(const uint4*)(xh + (size_t)r * D_DIM + ck * 8);
            vl = *(const uint4*)(xl + (size_t)r * D_DIM + ck * 8);
        }
        int boff = row * 256 + ((ck * 16) ^ ((row & 7) << 4));
        *(uint4*)((char*)(&a_s[0][0]) + boff) = vh;
        *(uint4*)((char*)(&a_s[1][0]) + boff) = vl;
    }
    __syncthreads();   // only barrier: K-loop is barrier-free (A fully resident)

    int lane = tid & 63;
    int wave = tid >> 6;            // 0..7, each owns 32 cols
    int l15 = lane & 15, q = lane >> 4;
    int colbase = blockIdx.x * 256 + wave * 32;

    const unsigned short* whp = wh + (size_t)e * N_DIM * D_DIM;
    // FIX (round 2 bug): wl = wh + E*N*D, so the hi->lo plane offset is E*N*D, not N*D.
    const size_t plane_stride = (size_t)E_NUM * N_DIM * D_DIM;   // whp -> wlp (same e)

    f32x4 acc[8][2];
    #pragma unroll
    for (int mi = 0; mi < 8; ++mi) {
        acc[mi][0] = (f32x4){0.f, 0.f, 0.f, 0.f};
        acc[mi][1] = (f32x4){0.f, 0.f, 0.f, 0.f};
    }

    // B base for this lane: col = colbase + {0,16} + l15, k offset q*8
    const unsigned short* base0 = whp + (size_t)(colbase + l15) * D_DIM + q * 8;

    bf16x8 cb0 = *(const bf16x8*)(base0);
    bf16x8 cb1 = *(const bf16x8*)(base0 + 16 * D_DIM);

    #pragma unroll
    for (int s = 0; s < 8; ++s) {
        bf16x8 nb0 = cb0, nb1 = cb1;
        if (s < 7) {
            int s1 = s + 1;
            const unsigned short* nb = base0 + ((s1 & 3) * 32) + ((s1 >= 4) ? plane_stride : 0);
            nb0 = *(const bf16x8*)(nb);
            nb1 = *(const bf16x8*)(nb + 16 * D_DIM);
        }
        const int kb = ((s & 3) * 32 + q * 8) * 2;   // byte offset in K within plane
        // x_hi plane (always): s<4 -> x_hi*W_hi, s>=4 -> x_hi*W_lo
        #pragma unroll
        for (int mi = 0; mi < 8; ++mi) {
            int row  = mi * 16 + l15;
            int aoff = row * 256 + (kb ^ ((row & 7) << 4));
            bf16x8 a = *(const bf16x8*)((const char*)(&a_s[0][0]) + aoff);
            acc[mi][0] = __builtin_amdgcn_mfma_f32_16x16x32_bf16(a, cb0, acc[mi][0], 0, 0, 0);
            acc[mi][1] = __builtin_amdgcn_mfma_f32_16x16x32_bf16(a, cb1, acc[mi][1], 0, 0, 0);
        }
        // x_lo plane (only with W_hi: steps 0..3) -- reuses cb0/cb1
        if (s < 4) {
            #pragma unroll
            for (int mi = 0; mi < 8; ++mi) {
                int row  = mi * 16 + l15;
                int aoff = row * 256 + (kb ^ ((row & 7) << 4));
                bf16x8 a = *(const bf16x8*)((const char*)(&a_s[1][0]) + aoff);
                acc[mi][0] = __builtin_amdgcn_mfma_f32_16x16x32_bf16(a, cb0, acc[mi][0], 0, 0, 0);
                acc[mi][1] = __builtin_amdgcn_mfma_f32_16x16x32_bf16(a, cb1, acc[mi][1], 0, 0, 0);
            }
        }
        cb0 = nb0; cb1 = nb1;
    }

    // epilogue: C/D layout col=lane&15, row=(lane>>4)*4+reg
    const float* bp = bias + (size_t)e * N_DIM;
    float bv0 = bp[colbase + l15];
    float bv1 = bp[colbase + 16 + l15];

    #pragma unroll
    for (int mi = 0; mi < 8; ++mi) {
        #pragma unroll
        for (int reg = 0; reg < 4; ++reg) {
            int m = mi * 16 + q * 4 + reg;
            if (m < cnt) {
                int r = sorted[seg + m];
                float* op = out + (size_t)r * N_DIM + colbase;
                op[l15]      = acc[mi][0][reg] + bv0;
                op[16 + l15] = acc[mi][1][reg] + bv1;
            }
        }
    }
}

// ---------------- fallback fp32 GEMM (workspace too small) ---------------

__device__ __forceinline__ void fma4(float4& ac, float xs, const float4& wv) {
    ac.x = fmaf(xs, wv.x, ac.x);
    ac.y = fmaf(xs, wv.y, ac.y);
    ac.z = fmaf(xs, wv.z, ac.z);
    ac.w = fmaf(xs, wv.w, ac.w);
}

__global__ __launch_bounds__(256)
void gemm_kernel(const float* __restrict__ x,
                 const float* __restrict__ W,
                 const float* __restrict__ bias,
                 const int* __restrict__ ws_i,
                 float* __restrict__ out) {
    int bt = blockIdx.y;
    if (bt >= ws_i[0]) return;
    int e   = ws_i[8 + bt];
    int seg = ws_i[96 + bt];
    int cnt = ws_i[184 + bt];
    const int* sorted = ws_i + 512;

    __shared__ float x_s[64][D_DIM];
    __shared__ int   rows_s[64];

    int tid = threadIdx.x;
    if (tid < 64) rows_s[tid] = (tid < cnt) ? sorted[seg + tid] : -1;
    __syncthreads();

    #pragma unroll
    for (int c = 0; c < 8; ++c) {
        int idx = c * 256 + tid;
        int i = idx >> 5;
        int k4 = idx & 31;
        int r = rows_s[i];
        float4 v;
        if (r >= 0) v = *(const float4*)(x + (size_t)r * D_DIM + k4 * 4);
        else        v = make_float4(0.f, 0.f, 0.f, 0.f);
        *(float4*)(&x_s[i][k4 * 4]) = v;
    }
    __syncthreads();

    int nidx = tid & 63;
    int mg   = tid >> 6;
    int col  = blockIdx.x * 256 + nidx * 4;
    const float* Wp = W + ((size_t)e * D_DIM) * N_DIM + col;

    float4 acc[16];
    #pragma unroll
    for (int i = 0; i < 16; ++i) acc[i] = make_float4(0.f, 0.f, 0.f, 0.f);

    for (int k = 0; k < D_DIM; k += 4) {
        float4 w0 = *(const float4*)(Wp + (size_t)(k + 0) * N_DIM);
        float4 w1 = *(const float4*)(Wp + (size_t)(k + 1) * N_DIM);
        float4 w2 = *(const float4*)(Wp + (size_t)(k + 2) * N_DIM);
        float4 w3 = *(const float4*)(Wp + (size_t)(k + 3) * N_DIM);
        #pragma unroll
        for (int i = 0; i < 16; ++i) {
            float4 xv = *(const float4*)(&x_s[mg * 16 + i][k]);
            fma4(acc[i], xv.x, w0);
            fma4(acc[i], xv.y, w1);
            fma4(acc[i], xv.z, w2);
            fma4(acc[i], xv.w, w3);
        }
    }

    float4 bv = *(const float4*)(bias + (size_t)e * N_DIM + col);
    #pragma unroll
    for (int i = 0; i < 16; ++i) {
        int m = mg * 16 + i;
        if (m < cnt) {
            int r = rows_s[m];
            float4 o = acc[i];
            o.x += bv.x; o.y += bv.y; o.z += bv.z; o.w += bv.w;
            *(float4*)(out + (size_t)r * N_DIM + col) = o;
        }
    }
}

// ---------------- softmax (unchanged) ---------------

__global__ __launch_bounds__(256)
void softmax_kernel(const float* __restrict__ x,
                    const float* __restrict__ tlo,
                    const float* __restrict__ thi,
                    float* __restrict__ out) {
    int r = blockIdx.x;
    int tid = threadIdx.x;
    float th = x[(size_t)r * D_DIM];
    bool valid = false;
    #pragma unroll
    for (int i = 0; i < E_NUM; ++i) {
        if (th > tlo[i] && th <= thi[i]) valid = true;
    }
    float* row = out + (size_t)r * N_DIM;

    if (!valid) {
        float4 z = make_float4(0.f, 0.f, 0.f, 0.f);
        #pragma unroll
        for (int c = 0; c < 8; ++c)
            *(float4*)(row + c * 1024 + tid * 4) = z;
        return;
    }

    float4 v[8];
    float mx = -INFINITY;
    #pragma unroll
    for (int c = 0; c < 8; ++c) {
        v[c] = *(const float4*)(row + c * 1024 + tid * 4);
        mx = fmaxf(mx, fmaxf(fmaxf(v[c].x, v[c].y), fmaxf(v[c].z, v[c].w)));
    }

    __shared__ float red[8];
    #pragma unroll
    for (int o = 1; o < 64; o <<= 1) mx = fmaxf(mx, __shfl_xor(mx, o));
    if ((tid & 63) == 0) red[tid >> 6] = mx;
    __syncthreads();
    mx = fmaxf(fmaxf(red[0], red[1]), fmaxf(red[2], red[3]));

    float sum = 0.f;
    #pragma unroll
    for (int c = 0; c < 8; ++c) {
        v[c].x = expf(v[c].x - mx);
        v[c].y = expf(v[c].y - mx);
        v[c].z = expf(v[c].z - mx);
        v[c].w = expf(v[c].w - mx);
        sum += v[c].x + v[c].y + v[c].z + v[c].w;
    }
    #pragma unroll
    for (int o = 1; o < 64; o <<= 1) sum += __shfl_xor(sum, o);
    if ((tid & 63) == 0) red[4 + (tid >> 6)] = sum;
    __syncthreads();
    sum = red[4] + red[5] + red[6] + red[7];

    float inv = 1.0f / sum;
    #pragma unroll
    for (int c = 0; c < 8; ++c) {
        float4 o;
        o.x = v[c].x * inv; o.y = v[c].y * inv;
        o.z = v[c].z * inv; o.w = v[c].w * inv;
        *(float4*)(row + c * 1024 + tid * 4) = o;
    }
}

extern "C" void kernel_launch(void* const* d_in, const int* in_sizes, int n_in,
                              void* d_out, int out_size, void* d_ws, size_t ws_size,
                              hipStream_t stream) {
    const float* x   = (const float*)d_in[0];
    const float* W   = (const float*)d_in[1];
    const float* b   = (const float*)d_in[2];
    const float* tlo = (const float*)d_in[3];
    const float* thi = (const float*)d_in[4];
    float* out = (float*)d_out;
    int* ws_i = (int*)d_ws;

    const size_t meta = 65536;
    const size_t xsz = (size_t)B_ROWS * D_DIM;
    const size_t wsz = (size_t)E_NUM * N_DIM * D_DIM;
    unsigned short* xh = (unsigned short*)((char*)d_ws + meta);
    unsigned short* xl = xh + xsz;
    unsigned short* wh = xl + xsz;
    unsigned short* wl = wh + wsz;
    size_t need = meta + (2 * xsz + 2 * wsz) * sizeof(unsigned short);
    bool fast = (ws_size >= need);

    bin_kernel<<<1, 1024, 0, stream>>>(x, tlo, thi, ws_i, fast ? 128 : 64);
    if (fast) {
        convert_kernel<<<1040, 256, 0, stream>>>(x, W, ws_i, xh, xl, wh, wl);
        // tiles <= 32 + 8 partials = 40
        gemm_mfma<<<dim3(N_DIM / 256, 40), 512, 0, stream>>>(xh, xl, wh, wl, b, ws_i, out);
    } else {
        gemm_kernel<<<dim3(N_DIM / 256, 72), 256, 0, stream>>>(x, W, b, ws_i, out);
    }
    softmax_kernel<<<B_ROWS, 256, 0, stream>>>(x, tlo, thi, out);
}

// Round 4
// 223.894 us; speedup vs baseline: 1.1176x; 1.1176x over previous
//
#include <hip/hip_runtime.h>
#include <math.h>

// Problem: E=8, B=4096, D=128, N=8192.
// out[b,n] = softmax_n( x[b,:] @ W[e(b)] + bias[e(b)] ) for the (unique) bin e(b), else 0.
//
// Round 4: undo the round-3 spill disaster (launch_bounds(512,4) forced 64 VGPR; acc alone
// needs 64 -> 275MB scratch writes). Back to the round-1-proven register regime:
//   - 256 threads, plain __launch_bounds__(256)  [round 1 measured: 128 VGPR, zero spill]
//   - tile 128x128, 4 waves in 1x4 col-split (wave = 128r x 32c, acc[8][2]=64 VGPR, no B dup)
//   - LDS holds ONLY x_hi (32 KB, XOR-swizzled) -> 4 blocks/CU = 4 waves/SIMD (2x round 1)
//   - x_lo fragments STREAMED from global (xl = 1 MB, L2-resident; 16-B loads per lane)
//   - W_hi fragment reused for both x_hi and x_lo MFMAs; depth-1 B prefetch
// Numeric path IDENTICAL to rounds 1/3: x*W ~= x_hi*W_hi + x_lo*W_hi + x_hi*W_lo.

#define B_ROWS 4096
#define D_DIM  128
#define N_DIM  8192
#define E_NUM  8

typedef __attribute__((ext_vector_type(8))) __bf16 bf16x8;
typedef __attribute__((ext_vector_type(4))) float  f32x4;

__device__ __forceinline__ unsigned short f2bf(float f) {
    unsigned int u = __float_as_uint(f);
    unsigned int r = u + 0x7FFFu + ((u >> 16) & 1u);   // round-to-nearest-even
    return (unsigned short)(r >> 16);
}
__device__ __forceinline__ float bf2f(unsigned short h) {
    return __uint_as_float(((unsigned int)h) << 16);
}

// ws int layout:
//   [0]         n_tiles
//   [8..79]     tile_e
//   [96..167]   tile_start
//   [184..255]  tile_cnt
//   [448..455]  per-expert counts
//   [512..4607] sorted row indices (grouped by expert)
// byte 65536+ : x_hi (1MB) | x_lo (1MB) | W_hi (16MB) | W_lo (16MB)   [bf16]

__global__ __launch_bounds__(1024)
void bin_kernel(const float* __restrict__ x,
                const float* __restrict__ tlo,
                const float* __restrict__ thi,
                int* __restrict__ ws_i, int m_tile) {
    __shared__ int cnt_s[E_NUM];
    __shared__ int off_s[E_NUM];
    __shared__ int cur_s[E_NUM];
    __shared__ int e_row[B_ROWS];

    int tid = threadIdx.x;
    if (tid < E_NUM) cnt_s[tid] = 0;
    __syncthreads();

    for (int r = tid; r < B_ROWS; r += 1024) {
        float th = x[(size_t)r * D_DIM];   // x[r, 0]
        int e = -1;
        #pragma unroll
        for (int i = 0; i < E_NUM; ++i) {
            if (e < 0 && th > tlo[i] && th <= thi[i]) e = i;  // first match
        }
        e_row[r] = e;
        if (e >= 0) atomicAdd(&cnt_s[e], 1);
    }
    __syncthreads();

    if (tid == 0) {
        int off = 0;
        for (int e = 0; e < E_NUM; ++e) {
            ws_i[448 + e] = cnt_s[e];
            off_s[e] = off;
            cur_s[e] = off;
            off += cnt_s[e];
        }
        int nt = 0;
        for (int e = 0; e < E_NUM; ++e) {
            int c = cnt_s[e];
            int s = off_s[e];
            for (int t0 = 0; t0 < c && nt < 72; t0 += m_tile) {
                ws_i[8 + nt]   = e;
                ws_i[96 + nt]  = s + t0;
                ws_i[184 + nt] = (c - t0 < m_tile) ? (c - t0) : m_tile;
                ++nt;
            }
        }
        ws_i[0] = nt;
    }
    __syncthreads();

    for (int r = tid; r < B_ROWS; r += 1024) {
        int e = e_row[r];
        if (e >= 0) {
            int p = atomicAdd(&cur_s[e], 1);
            ws_i[512 + p] = r;
        }
    }
}

// Split x and active experts' W into bf16 hi/lo. W output layout is TRANSPOSED to
// [e][n][k] (k contiguous) so MFMA B-fragments are 16B contiguous loads.
__global__ __launch_bounds__(256)
void convert_kernel(const float* __restrict__ x, const float* __restrict__ W,
                    const int* __restrict__ ws_i,
                    unsigned short* __restrict__ xh, unsigned short* __restrict__ xl,
                    unsigned short* __restrict__ wh, unsigned short* __restrict__ wl) {
    int bid = blockIdx.x;
    int t = threadIdx.x;
    if (bid < 1024) {
        int e = bid >> 7;                       // 8 experts x 128 n-chunks of 64
        if (ws_i[448 + e] == 0) return;         // expert inactive -> skip
        int n0 = (bid & 127) * 64;
        __shared__ __align__(16) unsigned short hi_s[64][136];  // stride 272B
        __shared__ __align__(16) unsigned short lo_s[64][136];
        const float* Wp = W + (size_t)e * D_DIM * N_DIM + n0;
        #pragma unroll
        for (int i = 0; i < 8; ++i) {
            int idx = i * 256 + t;              // 2048 float4 = 128 d-rows x 16
            int d  = idx >> 4;
            int j4 = idx & 15;
            float4 v = *(const float4*)(Wp + (size_t)d * N_DIM + j4 * 4);
            float fv[4] = {v.x, v.y, v.z, v.w};
            #pragma unroll
            for (int c = 0; c < 4; ++c) {
                unsigned short h = f2bf(fv[c]);
                hi_s[j4 * 4 + c][d] = h;
                lo_s[j4 * 4 + c][d] = f2bf(fv[c] - bf2f(h));
            }
        }
        __syncthreads();
        unsigned short* whp = wh + ((size_t)e * N_DIM + n0) * D_DIM;
        unsigned short* wlp = wl + ((size_t)e * N_DIM + n0) * D_DIM;
        #pragma unroll
        for (int i = 0; i < 4; ++i) {
            int idx = i * 256 + t;              // 1024 16B-chunks = 64 n-rows x 16
            int nl = idx >> 4;
            int ck = idx & 15;
            *(uint4*)(whp + (size_t)nl * D_DIM + ck * 8) = *(const uint4*)(&hi_s[nl][ck * 8]);
            *(uint4*)(wlp + (size_t)nl * D_DIM + ck * 8) = *(const uint4*)(&lo_s[nl][ck * 8]);
        }
    } else {
        // x split: 16 blocks cover 4096*128 floats, layout unchanged (k contiguous)
        int base = (bid - 1024) * 32768;
        for (int i = 0; i < 32; ++i) {
            int idx = base + (i * 256 + t) * 4;
            float4 v = *(const float4*)(x + idx);
            float fv[4] = {v.x, v.y, v.z, v.w};
            unsigned short hq[4], lq[4];
            #pragma unroll
            for (int c = 0; c < 4; ++c) {
                hq[c] = f2bf(fv[c]);
                lq[c] = f2bf(fv[c] - bf2f(hq[c]));
            }
            *(uint2*)(xh + idx) = *(const uint2*)hq;
            *(uint2*)(xl + idx) = *(const uint2*)lq;
        }
    }
}

// MFMA GEMM v4: block = 128 rows x 128 cols, 256 threads = 4 waves in 1x4 col-split
// (wave owns 32 distinct cols; acc[8][2] = 64 VGPR). x_hi in 32 KB swizzled LDS;
// x_lo streamed from global (L2-hot, 1 MB). K-loop: s=0..3 W_hi (used by x_hi AND x_lo
// MFMAs), s=4..7 W_lo (x_hi only). Depth-1 B prefetch. One barrier total.
__global__ __launch_bounds__(256)
void gemm_mfma(const unsigned short* __restrict__ xh, const unsigned short* __restrict__ xl,
               const unsigned short* __restrict__ wh, const unsigned short* __restrict__ wl,
               const float* __restrict__ bias, const int* __restrict__ ws_i,
               float* __restrict__ out) {
    int bt = blockIdx.y;
    if (bt >= ws_i[0]) return;
    int e   = ws_i[8 + bt];
    int seg = ws_i[96 + bt];
    int cnt = ws_i[184 + bt];
    const int* sorted = ws_i + 512;

    __shared__ __align__(16) unsigned short a_s[128 * 128];  // 32 KB (x_hi only)
    __shared__ int rows_s[128];

    int tid = threadIdx.x;
    if (tid < 128) rows_s[tid] = (tid < cnt) ? sorted[seg + tid] : -1;
    // stage gathered x_hi rows, XOR-swizzled: byte ^= (row&7)<<4
    #pragma unroll
    for (int i = 0; i < 8; ++i) {
        int idx = i * 256 + tid;     // 2048 chunks = 128 rows x 16 x 16B
        int row = idx >> 4;
        int ck  = idx & 15;
        uint4 vh = make_uint4(0, 0, 0, 0);
        if (row < cnt) {
            int r = sorted[seg + row];
            vh = *(const uint4*)(xh + (size_t)r * D_DIM + ck * 8);
        }
        int boff = row * 256 + ((ck * 16) ^ ((row & 7) << 4));
        *(uint4*)((char*)a_s + boff) = vh;
    }
    __syncthreads();   // only barrier: K-loop is barrier-free (A resident / streamed)

    int lane = tid & 63;
    int wave = tid >> 6;            // 0..3, each owns 32 cols
    int l15 = lane & 15, q = lane >> 4;
    int colbase = blockIdx.x * 128 + wave * 32;

    const unsigned short* whp = wh + (size_t)e * N_DIM * D_DIM;
    // wl = wh + E*N*D, so hi->lo plane offset is E*N*D (same expert).
    const size_t plane_stride = (size_t)E_NUM * N_DIM * D_DIM;

    // per-lane row indices for streamed x_lo fragments (row = mi*16 + l15)
    int r8[8];
    #pragma unroll
    for (int mi = 0; mi < 8; ++mi) r8[mi] = rows_s[mi * 16 + l15];

    f32x4 acc[8][2];
    #pragma unroll
    for (int mi = 0; mi < 8; ++mi) {
        acc[mi][0] = (f32x4){0.f, 0.f, 0.f, 0.f};
        acc[mi][1] = (f32x4){0.f, 0.f, 0.f, 0.f};
    }

    // B base for this lane: col = colbase + {0,16} + l15, k offset q*8
    const unsigned short* base0 = whp + (size_t)(colbase + l15) * D_DIM + q * 8;

    bf16x8 cb0 = *(const bf16x8*)(base0);
    bf16x8 cb1 = *(const bf16x8*)(base0 + 16 * D_DIM);

    #pragma unroll
    for (int s = 0; s < 8; ++s) {
        bf16x8 nb0 = cb0, nb1 = cb1;
        if (s < 7) {
            int s1 = s + 1;
            const unsigned short* nb = base0 + ((s1 & 3) * 32) + ((s1 >= 4) ? plane_stride : 0);
            nb0 = *(const bf16x8*)(nb);
            nb1 = *(const bf16x8*)(nb + 16 * D_DIM);
        }
        const int kk = (s & 3) * 32 + q * 8;         // element offset in K
        const int kb = kk * 2;                       // byte offset
        // x_hi (LDS) with current B plane: s<4 -> W_hi, s>=4 -> W_lo
        #pragma unroll
        for (int mi = 0; mi < 8; ++mi) {
            int row  = mi * 16 + l15;
            int aoff = row * 256 + (kb ^ ((row & 7) << 4));
            bf16x8 a = *(const bf16x8*)((const char*)a_s + aoff);
            acc[mi][0] = __builtin_amdgcn_mfma_f32_16x16x32_bf16(a, cb0, acc[mi][0], 0, 0, 0);
            acc[mi][1] = __builtin_amdgcn_mfma_f32_16x16x32_bf16(a, cb1, acc[mi][1], 0, 0, 0);
        }
        // x_lo (streamed from global, L2-hot) with W_hi only: steps 0..3, reuses cb0/cb1
        if (s < 4) {
            #pragma unroll
            for (int mi = 0; mi < 8; ++mi) {
                bf16x8 al = (bf16x8){0, 0, 0, 0, 0, 0, 0, 0};
                int r = r8[mi];
                if (r >= 0) al = *(const bf16x8*)(xl + (size_t)r * D_DIM + kk);
                acc[mi][0] = __builtin_amdgcn_mfma_f32_16x16x32_bf16(al, cb0, acc[mi][0], 0, 0, 0);
                acc[mi][1] = __builtin_amdgcn_mfma_f32_16x16x32_bf16(al, cb1, acc[mi][1], 0, 0, 0);
            }
        }
        cb0 = nb0; cb1 = nb1;
    }

    // epilogue: C/D layout col=lane&15, row=(lane>>4)*4+reg
    const float* bp = bias + (size_t)e * N_DIM;
    float bv0 = bp[colbase + l15];
    float bv1 = bp[colbase + 16 + l15];

    #pragma unroll
    for (int mi = 0; mi < 8; ++mi) {
        #pragma unroll
        for (int reg = 0; reg < 4; ++reg) {
            int m = mi * 16 + q * 4 + reg;
            if (m < cnt) {
                int r = rows_s[m];
                float* op = out + (size_t)r * N_DIM + colbase;
                op[l15]      = acc[mi][0][reg] + bv0;
                op[16 + l15] = acc[mi][1][reg] + bv1;
            }
        }
    }
}

// ---------------- fallback fp32 GEMM (workspace too small) ---------------

__device__ __forceinline__ void fma4(float4& ac, float xs, const float4& wv) {
    ac.x = fmaf(xs, wv.x, ac.x);
    ac.y = fmaf(xs, wv.y, ac.y);
    ac.z = fmaf(xs, wv.z, ac.z);
    ac.w = fmaf(xs, wv.w, ac.w);
}

__global__ __launch_bounds__(256)
void gemm_kernel(const float* __restrict__ x,
                 const float* __restrict__ W,
                 const float* __restrict__ bias,
                 const int* __restrict__ ws_i,
                 float* __restrict__ out) {
    int bt = blockIdx.y;
    if (bt >= ws_i[0]) return;
    int e   = ws_i[8 + bt];
    int seg = ws_i[96 + bt];
    int cnt = ws_i[184 + bt];
    const int* sorted = ws_i + 512;

    __shared__ float x_s[64][D_DIM];
    __shared__ int   rows_s[64];

    int tid = threadIdx.x;
    if (tid < 64) rows_s[tid] = (tid < cnt) ? sorted[seg + tid] : -1;
    __syncthreads();

    #pragma unroll
    for (int c = 0; c < 8; ++c) {
        int idx = c * 256 + tid;
        int i = idx >> 5;
        int k4 = idx & 31;
        int r = rows_s[i];
        float4 v;
        if (r >= 0) v = *(const float4*)(x + (size_t)r * D_DIM + k4 * 4);
        else        v = make_float4(0.f, 0.f, 0.f, 0.f);
        *(float4*)(&x_s[i][k4 * 4]) = v;
    }
    __syncthreads();

    int nidx = tid & 63;
    int mg   = tid >> 6;
    int col  = blockIdx.x * 256 + nidx * 4;
    const float* Wp = W + ((size_t)e * D_DIM) * N_DIM + col;

    float4 acc[16];
    #pragma unroll
    for (int i = 0; i < 16; ++i) acc[i] = make_float4(0.f, 0.f, 0.f, 0.f);

    for (int k = 0; k < D_DIM; k += 4) {
        float4 w0 = *(const float4*)(Wp + (size_t)(k + 0) * N_DIM);
        float4 w1 = *(const float4*)(Wp + (size_t)(k + 1) * N_DIM);
        float4 w2 = *(const float4*)(Wp + (size_t)(k + 2) * N_DIM);
        float4 w3 = *(const float4*)(Wp + (size_t)(k + 3) * N_DIM);
        #pragma unroll
        for (int i = 0; i < 16; ++i) {
            float4 xv = *(const float4*)(&x_s[mg * 16 + i][k]);
            fma4(acc[i], xv.x, w0);
            fma4(acc[i], xv.y, w1);
            fma4(acc[i], xv.z, w2);
            fma4(acc[i], xv.w, w3);
        }
    }

    float4 bv = *(const float4*)(bias + (size_t)e * N_DIM + col);
    #pragma unroll
    for (int i = 0; i < 16; ++i) {
        int m = mg * 16 + i;
        if (m < cnt) {
            int r = rows_s[m];
            float4 o = acc[i];
            o.x += bv.x; o.y += bv.y; o.z += bv.z; o.w += bv.w;
            *(float4*)(out + (size_t)r * N_DIM + col) = o;
        }
    }
}

// ---------------- softmax (unchanged) ---------------

__global__ __launch_bounds__(256)
void softmax_kernel(const float* __restrict__ x,
                    const float* __restrict__ tlo,
                    const float* __restrict__ thi,
                    float* __restrict__ out) {
    int r = blockIdx.x;
    int tid = threadIdx.x;
    float th = x[(size_t)r * D_DIM];
    bool valid = false;
    #pragma unroll
    for (int i = 0; i < E_NUM; ++i) {
        if (th > tlo[i] && th <= thi[i]) valid = true;
    }
    float* row = out + (size_t)r * N_DIM;

    if (!valid) {
        float4 z = make_float4(0.f, 0.f, 0.f, 0.f);
        #pragma unroll
        for (int c = 0; c < 8; ++c)
            *(float4*)(row + c * 1024 + tid * 4) = z;
        return;
    }

    float4 v[8];
    float mx = -INFINITY;
    #pragma unroll
    for (int c = 0; c < 8; ++c) {
        v[c] = *(const float4*)(row + c * 1024 + tid * 4);
        mx = fmaxf(mx, fmaxf(fmaxf(v[c].x, v[c].y), fmaxf(v[c].z, v[c].w)));
    }

    __shared__ float red[8];
    #pragma unroll
    for (int o = 1; o < 64; o <<= 1) mx = fmaxf(mx, __shfl_xor(mx, o));
    if ((tid & 63) == 0) red[tid >> 6] = mx;
    __syncthreads();
    mx = fmaxf(fmaxf(red[0], red[1]), fmaxf(red[2], red[3]));

    float sum = 0.f;
    #pragma unroll
    for (int c = 0; c < 8; ++c) {
        v[c].x = expf(v[c].x - mx);
        v[c].y = expf(v[c].y - mx);
        v[c].z = expf(v[c].z - mx);
        v[c].w = expf(v[c].w - mx);
        sum += v[c].x + v[c].y + v[c].z + v[c].w;
    }
    #pragma unroll
    for (int o = 1; o < 64; o <<= 1) sum += __shfl_xor(sum, o);
    if ((tid & 63) == 0) red[4 + (tid >> 6)] = sum;
    __syncthreads();
    sum = red[4] + red[5] + red[6] + red[7];

    float inv = 1.0f / sum;
    #pragma unroll
    for (int c = 0; c < 8; ++c) {
        float4 o;
        o.x = v[c].x * inv; o.y = v[c].y * inv;
        o.z = v[c].z * inv; o.w = v[c].w * inv;
        *(float4*)(row + c * 1024 + tid * 4) = o;
    }
}

extern "C" void kernel_launch(void* const* d_in, const int* in_sizes, int n_in,
                              void* d_out, int out_size, void* d_ws, size_t ws_size,
                              hipStream_t stream) {
    const float* x   = (const float*)d_in[0];
    const float* W   = (const float*)d_in[1];
    const float* b   = (const float*)d_in[2];
    const float* tlo = (const float*)d_in[3];
    const float* thi = (const float*)d_in[4];
    float* out = (float*)d_out;
    int* ws_i = (int*)d_ws;

    const size_t meta = 65536;
    const size_t xsz = (size_t)B_ROWS * D_DIM;
    const size_t wsz = (size_t)E_NUM * N_DIM * D_DIM;
    unsigned short* xh = (unsigned short*)((char*)d_ws + meta);
    unsigned short* xl = xh + xsz;
    unsigned short* wh = xl + xsz;
    unsigned short* wl = wh + wsz;
    size_t need = meta + (2 * xsz + 2 * wsz) * sizeof(unsigned short);
    bool fast = (ws_size >= need);

    bin_kernel<<<1, 1024, 0, stream>>>(x, tlo, thi, ws_i, fast ? 128 : 64);
    if (fast) {
        convert_kernel<<<1040, 256, 0, stream>>>(x, W, ws_i, xh, xl, wh, wl);
        // tiles <= 32 full + 8 partials = 40
        gemm_mfma<<<dim3(N_DIM / 128, 40), 256, 0, stream>>>(xh, xl, wh, wl, b, ws_i, out);
    } else {
        gemm_kernel<<<dim3(N_DIM / 256, 72), 256, 0, stream>>>(x, W, b, ws_i, out);
    }
    softmax_kernel<<<B_ROWS, 256, 0, stream>>>(x, tlo, thi, out);
}

// Round 5
// 138.207 us; speedup vs baseline: 1.8105x; 1.6200x over previous
//
#include <hip/hip_runtime.h>
#include <math.h>

// Problem: E=8, B=4096, D=128, N=8192.
// out[b,n] = softmax_n( x[b,:] @ W[e(b)] + bias[e(b)] ) for the (unique) bin e(b), else 0.
//
// Round 5 = round-1 proven body (both x planes resident in 64KB LDS, barrier-free K-loop)
// + three fixes to its measured limiters (MfmaUtil 14%, depth-0 B loads, 2x B duplication):
//   1. 1x4 col-split waves: each B fragment loaded once per block (round 1: twice).
//   2. W_hi fragment reused for BOTH x_hi and x_lo MFMAs -> 8 K-steps, 12 MFMA per B load.
//   3. Depth-2 B prefetch (3-slot rotating buffer, compile-time indices after full unroll).
// Round-4 lesson kept: NO per-lane gathered streams in the inner loop.
// Round-3 lesson kept: plain __launch_bounds__(256), never force min-waves (spills).
// Numeric path IDENTICAL to rounds 1/3/4: x*W ~= x_hi*W_hi + x_lo*W_hi + x_hi*W_lo.

#define B_ROWS 4096
#define D_DIM  128
#define N_DIM  8192
#define E_NUM  8

typedef __attribute__((ext_vector_type(8))) __bf16 bf16x8;
typedef __attribute__((ext_vector_type(4))) float  f32x4;

__device__ __forceinline__ unsigned short f2bf(float f) {
    unsigned int u = __float_as_uint(f);
    unsigned int r = u + 0x7FFFu + ((u >> 16) & 1u);   // round-to-nearest-even
    return (unsigned short)(r >> 16);
}
__device__ __forceinline__ float bf2f(unsigned short h) {
    return __uint_as_float(((unsigned int)h) << 16);
}

// ws int layout:
//   [0]         n_tiles
//   [8..79]     tile_e
//   [96..167]   tile_start
//   [184..255]  tile_cnt
//   [448..455]  per-expert counts
//   [512..4607] sorted row indices (grouped by expert)
// byte 65536+ : x_hi (1MB) | x_lo (1MB) | W_hi (16MB) | W_lo (16MB)   [bf16]

__global__ __launch_bounds__(1024)
void bin_kernel(const float* __restrict__ x,
                const float* __restrict__ tlo,
                const float* __restrict__ thi,
                int* __restrict__ ws_i, int m_tile) {
    __shared__ int cnt_s[E_NUM];
    __shared__ int off_s[E_NUM];
    __shared__ int cur_s[E_NUM];
    __shared__ int e_row[B_ROWS];

    int tid = threadIdx.x;
    if (tid < E_NUM) cnt_s[tid] = 0;
    __syncthreads();

    for (int r = tid; r < B_ROWS; r += 1024) {
        float th = x[(size_t)r * D_DIM];   // x[r, 0]
        int e = -1;
        #pragma unroll
        for (int i = 0; i < E_NUM; ++i) {
            if (e < 0 && th > tlo[i] && th <= thi[i]) e = i;  // first match
        }
        e_row[r] = e;
        if (e >= 0) atomicAdd(&cnt_s[e], 1);
    }
    __syncthreads();

    if (tid == 0) {
        int off = 0;
        for (int e = 0; e < E_NUM; ++e) {
            ws_i[448 + e] = cnt_s[e];
            off_s[e] = off;
            cur_s[e] = off;
            off += cnt_s[e];
        }
        int nt = 0;
        for (int e = 0; e < E_NUM; ++e) {
            int c = cnt_s[e];
            int s = off_s[e];
            for (int t0 = 0; t0 < c && nt < 72; t0 += m_tile) {
                ws_i[8 + nt]   = e;
                ws_i[96 + nt]  = s + t0;
                ws_i[184 + nt] = (c - t0 < m_tile) ? (c - t0) : m_tile;
                ++nt;
            }
        }
        ws_i[0] = nt;
    }
    __syncthreads();

    for (int r = tid; r < B_ROWS; r += 1024) {
        int e = e_row[r];
        if (e >= 0) {
            int p = atomicAdd(&cur_s[e], 1);
            ws_i[512 + p] = r;
        }
    }
}

// Split x and active experts' W into bf16 hi/lo. W output layout is TRANSPOSED to
// [e][n][k] (k contiguous) so MFMA B-fragments are 16B contiguous loads.
__global__ __launch_bounds__(256)
void convert_kernel(const float* __restrict__ x, const float* __restrict__ W,
                    const int* __restrict__ ws_i,
                    unsigned short* __restrict__ xh, unsigned short* __restrict__ xl,
                    unsigned short* __restrict__ wh, unsigned short* __restrict__ wl) {
    int bid = blockIdx.x;
    int t = threadIdx.x;
    if (bid < 1024) {
        int e = bid >> 7;                       // 8 experts x 128 n-chunks of 64
        if (ws_i[448 + e] == 0) return;         // expert inactive -> skip
        int n0 = (bid & 127) * 64;
        __shared__ __align__(16) unsigned short hi_s[64][136];  // stride 272B
        __shared__ __align__(16) unsigned short lo_s[64][136];
        const float* Wp = W + (size_t)e * D_DIM * N_DIM + n0;
        #pragma unroll
        for (int i = 0; i < 8; ++i) {
            int idx = i * 256 + t;              // 2048 float4 = 128 d-rows x 16
            int d  = idx >> 4;
            int j4 = idx & 15;
            float4 v = *(const float4*)(Wp + (size_t)d * N_DIM + j4 * 4);
            float fv[4] = {v.x, v.y, v.z, v.w};
            #pragma unroll
            for (int c = 0; c < 4; ++c) {
                unsigned short h = f2bf(fv[c]);
                hi_s[j4 * 4 + c][d] = h;
                lo_s[j4 * 4 + c][d] = f2bf(fv[c] - bf2f(h));
            }
        }
        __syncthreads();
        unsigned short* whp = wh + ((size_t)e * N_DIM + n0) * D_DIM;
        unsigned short* wlp = wl + ((size_t)e * N_DIM + n0) * D_DIM;
        #pragma unroll
        for (int i = 0; i < 4; ++i) {
            int idx = i * 256 + t;              // 1024 16B-chunks = 64 n-rows x 16
            int nl = idx >> 4;
            int ck = idx & 15;
            *(uint4*)(whp + (size_t)nl * D_DIM + ck * 8) = *(const uint4*)(&hi_s[nl][ck * 8]);
            *(uint4*)(wlp + (size_t)nl * D_DIM + ck * 8) = *(const uint4*)(&lo_s[nl][ck * 8]);
        }
    } else {
        // x split: 16 blocks cover 4096*128 floats, layout unchanged (k contiguous)
        int base = (bid - 1024) * 32768;
        for (int i = 0; i < 32; ++i) {
            int idx = base + (i * 256 + t) * 4;
            float4 v = *(const float4*)(x + idx);
            float fv[4] = {v.x, v.y, v.z, v.w};
            unsigned short hq[4], lq[4];
            #pragma unroll
            for (int c = 0; c < 4; ++c) {
                hq[c] = f2bf(fv[c]);
                lq[c] = f2bf(fv[c] - bf2f(hq[c]));
            }
            *(uint2*)(xh + idx) = *(const uint2*)hq;
            *(uint2*)(xl + idx) = *(const uint2*)lq;
        }
    }
}

// MFMA GEMM v5: block = 128 rows x 128 cols, 256 threads = 4 waves in 1x4 col-split
// (wave owns 32 distinct cols -> each B fragment loaded exactly once per block).
// Both x planes resident in 64KB XOR-swizzled LDS (round-1 proven). K-loop: 8 steps,
// s=0..3 W_hi (feeds x_hi AND x_lo MFMAs: 32 MFMA / 2 loads), s=4..7 W_lo (x_hi only).
// Depth-2 B prefetch via 3-slot rotating buffer. One barrier total.
__global__ __launch_bounds__(256)
void gemm_mfma(const unsigned short* __restrict__ xh, const unsigned short* __restrict__ xl,
               const unsigned short* __restrict__ wh, const unsigned short* __restrict__ wl,
               const float* __restrict__ bias, const int* __restrict__ ws_i,
               float* __restrict__ out) {
    int bt = blockIdx.y;
    if (bt >= ws_i[0]) return;
    int e   = ws_i[8 + bt];
    int seg = ws_i[96 + bt];
    int cnt = ws_i[184 + bt];
    const int* sorted = ws_i + 512;

    __shared__ __align__(16) unsigned short a_s[2][128 * 128];  // exactly 64 KB

    int tid = threadIdx.x;
    // stage gathered x_hi/x_lo rows, XOR-swizzled: byte ^= (row&7)<<4
    #pragma unroll
    for (int i = 0; i < 8; ++i) {
        int idx = i * 256 + tid;     // 2048 chunks = 128 rows x 16 x 16B
        int row = idx >> 4;
        int ck  = idx & 15;
        uint4 vh = make_uint4(0, 0, 0, 0), vl = make_uint4(0, 0, 0, 0);
        if (row < cnt) {
            int r = sorted[seg + row];
            vh = *(const uint4*)(xh + (size_t)r * D_DIM + ck * 8);
            vl = *(const uint4*)(xl + (size_t)r * D_DIM + ck * 8);
        }
        int boff = row * 256 + ((ck * 16) ^ ((row & 7) << 4));
        *(uint4*)((char*)(&a_s[0][0]) + boff) = vh;
        *(uint4*)((char*)(&a_s[1][0]) + boff) = vl;
    }
    __syncthreads();   // only barrier: K-loop is barrier-free (A fully resident)

    int lane = tid & 63;
    int wave = tid >> 6;            // 0..3, each owns 32 cols
    int l15 = lane & 15, q = lane >> 4;
    int colbase = blockIdx.x * 128 + wave * 32;

    const unsigned short* whp = wh + (size_t)e * N_DIM * D_DIM;
    // wl = wh + E*N*D, so hi->lo plane offset is E*N*D (same expert).
    const size_t plane_stride = (size_t)E_NUM * N_DIM * D_DIM;

    f32x4 acc[8][2];
    #pragma unroll
    for (int mi = 0; mi < 8; ++mi) {
        acc[mi][0] = (f32x4){0.f, 0.f, 0.f, 0.f};
        acc[mi][1] = (f32x4){0.f, 0.f, 0.f, 0.f};
    }

    // B base for this lane: col = colbase + {0,16} + l15, k offset q*8
    const unsigned short* base0 = whp + (size_t)(colbase + l15) * D_DIM + q * 8;

    auto bload = [&](int s, bf16x8& b0, bf16x8& b1) {
        const unsigned short* p = base0 + (s & 3) * 32 + ((s >= 4) ? plane_stride : (size_t)0);
        b0 = *(const bf16x8*)(p);
        b1 = *(const bf16x8*)(p + 16 * D_DIM);
    };

    // 3-slot rotating B buffer, depth-2 prefetch (indices compile-time after full unroll)
    bf16x8 bq[3][2];
    bload(0, bq[0][0], bq[0][1]);
    bload(1, bq[1][0], bq[1][1]);

    #pragma unroll
    for (int s = 0; s < 8; ++s) {
        if (s < 6) bload(s + 2, bq[(s + 2) % 3][0], bq[(s + 2) % 3][1]);
        bf16x8 c0 = bq[s % 3][0];
        bf16x8 c1 = bq[s % 3][1];
        const int kb = ((s & 3) * 32 + q * 8) * 2;   // byte offset in K within plane
        #pragma unroll
        for (int mi = 0; mi < 8; ++mi) {
            int row  = mi * 16 + l15;
            int aoff = row * 256 + (kb ^ ((row & 7) << 4));
            bf16x8 ah = *(const bf16x8*)((const char*)(&a_s[0][0]) + aoff);
            acc[mi][0] = __builtin_amdgcn_mfma_f32_16x16x32_bf16(ah, c0, acc[mi][0], 0, 0, 0);
            acc[mi][1] = __builtin_amdgcn_mfma_f32_16x16x32_bf16(ah, c1, acc[mi][1], 0, 0, 0);
            if (s < 4) {   // x_lo * W_hi, reusing c0/c1
                bf16x8 al = *(const bf16x8*)((const char*)(&a_s[1][0]) + aoff);
                acc[mi][0] = __builtin_amdgcn_mfma_f32_16x16x32_bf16(al, c0, acc[mi][0], 0, 0, 0);
                acc[mi][1] = __builtin_amdgcn_mfma_f32_16x16x32_bf16(al, c1, acc[mi][1], 0, 0, 0);
            }
        }
    }

    // epilogue: C/D layout col=lane&15, row=(lane>>4)*4+reg
    const float* bp = bias + (size_t)e * N_DIM;
    float bv0 = bp[colbase + l15];
    float bv1 = bp[colbase + 16 + l15];

    #pragma unroll
    for (int mi = 0; mi < 8; ++mi) {
        #pragma unroll
        for (int reg = 0; reg < 4; ++reg) {
            int m = mi * 16 + q * 4 + reg;
            if (m < cnt) {
                int r = sorted[seg + m];
                float* op = out + (size_t)r * N_DIM + colbase;
                op[l15]      = acc[mi][0][reg] + bv0;
                op[16 + l15] = acc[mi][1][reg] + bv1;
            }
        }
    }
}

// ---------------- fallback fp32 GEMM (workspace too small) ---------------

__device__ __forceinline__ void fma4(float4& ac, float xs, const float4& wv) {
    ac.x = fmaf(xs, wv.x, ac.x);
    ac.y = fmaf(xs, wv.y, ac.y);
    ac.z = fmaf(xs, wv.z, ac.z);
    ac.w = fmaf(xs, wv.w, ac.w);
}

__global__ __launch_bounds__(256)
void gemm_kernel(const float* __restrict__ x,
                 const float* __restrict__ W,
                 const float* __restrict__ bias,
                 const int* __restrict__ ws_i,
                 float* __restrict__ out) {
    int bt = blockIdx.y;
    if (bt >= ws_i[0]) return;
    int e   = ws_i[8 + bt];
    int seg = ws_i[96 + bt];
    int cnt = ws_i[184 + bt];
    const int* sorted = ws_i + 512;

    __shared__ float x_s[64][D_DIM];
    __shared__ int   rows_s[64];

    int tid = threadIdx.x;
    if (tid < 64) rows_s[tid] = (tid < cnt) ? sorted[seg + tid] : -1;
    __syncthreads();

    #pragma unroll
    for (int c = 0; c < 8; ++c) {
        int idx = c * 256 + tid;
        int i = idx >> 5;
        int k4 = idx & 31;
        int r = rows_s[i];
        float4 v;
        if (r >= 0) v = *(const float4*)(x + (size_t)r * D_DIM + k4 * 4);
        else        v = make_float4(0.f, 0.f, 0.f, 0.f);
        *(float4*)(&x_s[i][k4 * 4]) = v;
    }
    __syncthreads();

    int nidx = tid & 63;
    int mg   = tid >> 6;
    int col  = blockIdx.x * 256 + nidx * 4;
    const float* Wp = W + ((size_t)e * D_DIM) * N_DIM + col;

    float4 acc[16];
    #pragma unroll
    for (int i = 0; i < 16; ++i) acc[i] = make_float4(0.f, 0.f, 0.f, 0.f);

    for (int k = 0; k < D_DIM; k += 4) {
        float4 w0 = *(const float4*)(Wp + (size_t)(k + 0) * N_DIM);
        float4 w1 = *(const float4*)(Wp + (size_t)(k + 1) * N_DIM);
        float4 w2 = *(const float4*)(Wp + (size_t)(k + 2) * N_DIM);
        float4 w3 = *(const float4*)(Wp + (size_t)(k + 3) * N_DIM);
        #pragma unroll
        for (int i = 0; i < 16; ++i) {
            float4 xv = *(const float4*)(&x_s[mg * 16 + i][k]);
            fma4(acc[i], xv.x, w0);
            fma4(acc[i], xv.y, w1);
            fma4(acc[i], xv.z, w2);
            fma4(acc[i], xv.w, w3);
        }
    }

    float4 bv = *(const float4*)(bias + (size_t)e * N_DIM + col);
    #pragma unroll
    for (int i = 0; i < 16; ++i) {
        int m = mg * 16 + i;
        if (m < cnt) {
            int r = rows_s[m];
            float4 o = acc[i];
            o.x += bv.x; o.y += bv.y; o.z += bv.z; o.w += bv.w;
            *(float4*)(out + (size_t)r * N_DIM + col) = o;
        }
    }
}

// ---------------- softmax (unchanged) ---------------

__global__ __launch_bounds__(256)
void softmax_kernel(const float* __restrict__ x,
                    const float* __restrict__ tlo,
                    const float* __restrict__ thi,
                    float* __restrict__ out) {
    int r = blockIdx.x;
    int tid = threadIdx.x;
    float th = x[(size_t)r * D_DIM];
    bool valid = false;
    #pragma unroll
    for (int i = 0; i < E_NUM; ++i) {
        if (th > tlo[i] && th <= thi[i]) valid = true;
    }
    float* row = out + (size_t)r * N_DIM;

    if (!valid) {
        float4 z = make_float4(0.f, 0.f, 0.f, 0.f);
        #pragma unroll
        for (int c = 0; c < 8; ++c)
            *(float4*)(row + c * 1024 + tid * 4) = z;
        return;
    }

    float4 v[8];
    float mx = -INFINITY;
    #pragma unroll
    for (int c = 0; c < 8; ++c) {
        v[c] = *(const float4*)(row + c * 1024 + tid * 4);
        mx = fmaxf(mx, fmaxf(fmaxf(v[c].x, v[c].y), fmaxf(v[c].z, v[c].w)));
    }

    __shared__ float red[8];
    #pragma unroll
    for (int o = 1; o < 64; o <<= 1) mx = fmaxf(mx, __shfl_xor(mx, o));
    if ((tid & 63) == 0) red[tid >> 6] = mx;
    __syncthreads();
    mx = fmaxf(fmaxf(red[0], red[1]), fmaxf(red[2], red[3]));

    float sum = 0.f;
    #pragma unroll
    for (int c = 0; c < 8; ++c) {
        v[c].x = expf(v[c].x - mx);
        v[c].y = expf(v[c].y - mx);
        v[c].z = expf(v[c].z - mx);
        v[c].w = expf(v[c].w - mx);
        sum += v[c].x + v[c].y + v[c].z + v[c].w;
    }
    #pragma unroll
    for (int o = 1; o < 64; o <<= 1) sum += __shfl_xor(sum, o);
    if ((tid & 63) == 0) red[4 + (tid >> 6)] = sum;
    __syncthreads();
    sum = red[4] + red[5] + red[6] + red[7];

    float inv = 1.0f / sum;
    #pragma unroll
    for (int c = 0; c < 8; ++c) {
        float4 o;
        o.x = v[c].x * inv; o.y = v[c].y * inv;
        o.z = v[c].z * inv; o.w = v[c].w * inv;
        *(float4*)(row + c * 1024 + tid * 4) = o;
    }
}

extern "C" void kernel_launch(void* const* d_in, const int* in_sizes, int n_in,
                              void* d_out, int out_size, void* d_ws, size_t ws_size,
                              hipStream_t stream) {
    const float* x   = (const float*)d_in[0];
    const float* W   = (const float*)d_in[1];
    const float* b   = (const float*)d_in[2];
    const float* tlo = (const float*)d_in[3];
    const float* thi = (const float*)d_in[4];
    float* out = (float*)d_out;
    int* ws_i = (int*)d_ws;

    const size_t meta = 65536;
    const size_t xsz = (size_t)B_ROWS * D_DIM;
    const size_t wsz = (size_t)E_NUM * N_DIM * D_DIM;
    unsigned short* xh = (unsigned short*)((char*)d_ws + meta);
    unsigned short* xl = xh + xsz;
    unsigned short* wh = xl + xsz;
    unsigned short* wl = wh + wsz;
    size_t need = meta + (2 * xsz + 2 * wsz) * sizeof(unsigned short);
    bool fast = (ws_size >= need);

    bin_kernel<<<1, 1024, 0, stream>>>(x, tlo, thi, ws_i, fast ? 128 : 64);
    if (fast) {
        convert_kernel<<<1040, 256, 0, stream>>>(x, W, ws_i, xh, xl, wh, wl);
        // tiles <= 32 full + 8 partials = 40
        gemm_mfma<<<dim3(N_DIM / 128, 40), 256, 0, stream>>>(xh, xl, wh, wl, b, ws_i, out);
    } else {
        gemm_kernel<<<dim3(N_DIM / 256, 72), 256, 0, stream>>>(x, W, b, ws_i, out);
    }
    softmax_kernel<<<B_ROWS, 256, 0, stream>>>(x, tlo, thi, out);
}